// Round 1
// baseline (1125.710 us; speedup 1.0000x reference)
//
#include <hip/hip_runtime.h>
#include <hip/hip_bf16.h>

typedef __attribute__((ext_vector_type(8))) short short8;
typedef __attribute__((ext_vector_type(4))) float floatx4;

// ---------- helpers ----------
__device__ __forceinline__ unsigned short f32_to_bf16(float f) {
    unsigned int u = __builtin_bit_cast(unsigned int, f);
    u = (u + 0x7FFFu + ((u >> 16) & 1u)) >> 16;   // RNE
    return (unsigned short)u;
}
__device__ __forceinline__ unsigned int pack_bf16x2(float lo, float hi) {
    return (unsigned int)f32_to_bf16(lo) | ((unsigned int)f32_to_bf16(hi) << 16);
}
__device__ __forceinline__ float bf16_to_f32(unsigned short h) {
    unsigned int u = ((unsigned int)h) << 16;
    return __builtin_bit_cast(float, u);
}

// ---------- transpose + cast: W fp32 [K][N] -> Wt bf16 [N][K] ----------
__global__ __launch_bounds__(256) void transpose_cast_kernel(
    const float* __restrict__ W, unsigned short* __restrict__ Wt, int K, int N) {
    __shared__ float tile[32][33];
    int n0 = blockIdx.x * 32;
    int k0 = blockIdx.y * 32;
    int tx = threadIdx.x & 31;
    int ty = threadIdx.x >> 5;           // 0..7
#pragma unroll
    for (int p = 0; p < 4; ++p) {
        int r = ty + 8 * p;
        tile[r][tx] = W[(long)(k0 + r) * N + n0 + tx];
    }
    __syncthreads();
#pragma unroll
    for (int p = 0; p < 4; ++p) {
        int r = ty + 8 * p;
        Wt[(long)(n0 + r) * K + k0 + tx] = f32_to_bf16(tile[tx][r]);
    }
}

// ---------- GEMM: C[M,N] = A[M,K](fp32) @ Bt[N,K](bf16)^T ----------
// 128x128 block tile, BK=32, 256 threads (4 waves), each wave 64x64 via
// 4x4 grid of 16x16x32 bf16 MFMAs. out_bf16: store bf16, else fp32 (+bias).
#define LDSS 40   // LDS row stride in elems (80B, 16B-aligned, conflict-free b128)

__global__ __launch_bounds__(256, 2) void gemm_kernel(
    const float* __restrict__ A, const unsigned short* __restrict__ Bt,
    void* __restrict__ C, const float* __restrict__ bias,
    int M, int N, int K, int out_bf16) {
    __shared__ unsigned short As[128 * LDSS];
    __shared__ unsigned short Bs[128 * LDSS];

    const int tid  = threadIdx.x;
    const int wave = tid >> 6;
    const int lane = tid & 63;
    const int m0 = blockIdx.x * 128;
    const int n0 = blockIdx.y * 128;
    const int wrow = (wave >> 1) * 64;
    const int wcol = (wave & 1) * 64;

    floatx4 acc[4][4];
#pragma unroll
    for (int i = 0; i < 4; ++i)
#pragma unroll
        for (int j = 0; j < 4; ++j) acc[i][j] = (floatx4)0.0f;

    // staging: each thread covers 16 consecutive k of one row (A: fp32->bf16, B: bf16)
    const int srow = tid >> 1;            // 0..127
    const int scol = (tid & 1) * 16;      // 0 or 16
    const float*          aptr = A  + (long)(m0 + srow) * K + scol;
    const unsigned short* bptr = Bt + (long)(n0 + srow) * K + scol;
    unsigned short* as_dst = &As[srow * LDSS + scol];
    unsigned short* bs_dst = &Bs[srow * LDSS + scol];

    const int frm = lane & 15;            // row within 16x16 tile
    const int fk  = (lane >> 4) * 8;      // k offset of this quad

    for (int kk = 0; kk < K; kk += 32) {
        float4 a0 = *(const float4*)(aptr + kk);
        float4 a1 = *(const float4*)(aptr + kk + 4);
        float4 a2 = *(const float4*)(aptr + kk + 8);
        float4 a3 = *(const float4*)(aptr + kk + 12);
        uint4  b0 = *(const uint4*)(bptr + kk);
        uint4  b1 = *(const uint4*)(bptr + kk + 8);

        uint4 ap0, ap1;
        ap0.x = pack_bf16x2(a0.x, a0.y); ap0.y = pack_bf16x2(a0.z, a0.w);
        ap0.z = pack_bf16x2(a1.x, a1.y); ap0.w = pack_bf16x2(a1.z, a1.w);
        ap1.x = pack_bf16x2(a2.x, a2.y); ap1.y = pack_bf16x2(a2.z, a2.w);
        ap1.z = pack_bf16x2(a3.x, a3.y); ap1.w = pack_bf16x2(a3.z, a3.w);

        __syncthreads();   // previous compute done before overwrite
        *(uint4*)as_dst       = ap0;
        *(uint4*)(as_dst + 8) = ap1;
        *(uint4*)bs_dst       = b0;
        *(uint4*)(bs_dst + 8) = b1;
        __syncthreads();   // staging visible

        short8 afrag[4], bfrag[4];
#pragma unroll
        for (int rt = 0; rt < 4; ++rt)
            afrag[rt] = *(const short8*)&As[(wrow + rt * 16 + frm) * LDSS + fk];
#pragma unroll
        for (int ct = 0; ct < 4; ++ct)
            bfrag[ct] = *(const short8*)&Bs[(wcol + ct * 16 + frm) * LDSS + fk];
#pragma unroll
        for (int rt = 0; rt < 4; ++rt)
#pragma unroll
            for (int ct = 0; ct < 4; ++ct)
                acc[rt][ct] = __builtin_amdgcn_mfma_f32_16x16x32_bf16(
                    afrag[rt], bfrag[ct], acc[rt][ct], 0, 0, 0);
    }

    // epilogue: C/D layout col=lane&15, row=(lane>>4)*4+r
    const int orow0 = m0 + wrow + (lane >> 4) * 4;
    const int ocol0 = n0 + wcol + (lane & 15);
    if (out_bf16) {
        unsigned short* Cb = (unsigned short*)C;
#pragma unroll
        for (int rt = 0; rt < 4; ++rt)
#pragma unroll
            for (int r = 0; r < 4; ++r) {
                long row = orow0 + rt * 16 + r;
#pragma unroll
                for (int ct = 0; ct < 4; ++ct)
                    Cb[row * N + ocol0 + ct * 16] = f32_to_bf16(acc[rt][ct][r]);
            }
    } else {
        float* Cf = (float*)C;
#pragma unroll
        for (int rt = 0; rt < 4; ++rt)
#pragma unroll
            for (int r = 0; r < 4; ++r) {
                long row = orow0 + rt * 16 + r;
#pragma unroll
                for (int ct = 0; ct < 4; ++ct) {
                    int col = ocol0 + ct * 16;
                    float v = acc[rt][ct][r];
                    if (bias) v += bias[col];
                    Cf[row * N + col] = v;
                }
            }
    }
}

// ---------- attention: 1 wave per (b,h,i); 32 keys at j = i + 128t ----------
__global__ __launch_bounds__(256) void attn_kernel(
    const float* __restrict__ q,            // [2048,1024] fp32
    const unsigned short* __restrict__ kv,  // [65536,2048] bf16 (k: cols 0..1023, v: 1024..2047)
    float* __restrict__ attn) {             // [2048,1024] fp32
    const int wave = threadIdx.x >> 6;
    const int lane = threadIdx.x & 63;
    const int flat = blockIdx.x * 4 + wave;   // 0..32767
    const int b = flat >> 11;
    const int h = (flat >> 7) & 15;
    const int i = flat & 127;
    const int d = lane;

    const float qv = q[(long)(b * 128 + i) * 1024 + h * 64 + d];
    const float scale = 0.125f;   // 64^-0.5

    float vreg[32], sc[32];
#pragma unroll
    for (int t = 0; t < 32; ++t) {
        long base = ((long)b * 4096 + i + t * 128) * 2048 + h * 64;
        float kd = bf16_to_f32(kv[base + d]);
        vreg[t]  = bf16_to_f32(kv[base + 1024 + d]);
        float p = qv * kd;
#pragma unroll
        for (int off = 32; off > 0; off >>= 1) p += __shfl_xor(p, off, 64);
        sc[t] = p * scale;
    }
    float mx = sc[0];
#pragma unroll
    for (int t = 1; t < 32; ++t) mx = fmaxf(mx, sc[t]);
    float denom = 0.0f;
#pragma unroll
    for (int t = 0; t < 32; ++t) { sc[t] = __expf(sc[t] - mx); denom += sc[t]; }
    float inv = 1.0f / denom;
    float acc = 0.0f;
#pragma unroll
    for (int t = 0; t < 32; ++t) acc += sc[t] * vreg[t];
    attn[(long)(b * 128 + i) * 1024 + h * 64 + d] = acc * inv;
}

// ---------- launch ----------
extern "C" void kernel_launch(void* const* d_in, const int* in_sizes, int n_in,
                              void* d_out, int out_size, void* d_ws, size_t ws_size,
                              hipStream_t stream) {
    const float* x       = (const float*)d_in[0];   // [16,128,1024]
    const float* context = (const float*)d_in[1];   // [16,4096,1024]
    const float* Wq      = (const float*)d_in[2];   // [1024,1024]
    const float* Wkv     = (const float*)d_in[3];   // [1024,2048]
    const float* Wout    = (const float*)d_in[4];   // [1024,1024]
    const float* bout    = (const float*)d_in[5];   // [1024]
    float* out = (float*)d_out;                     // [16,128,1024] fp32

    char* ws = (char*)d_ws;
    unsigned short* WqT   = (unsigned short*)(ws);                        // 2MB
    unsigned short* WkvT  = (unsigned short*)(ws + (2ll  << 20));         // 4MB
    unsigned short* WoutT = (unsigned short*)(ws + (6ll  << 20));         // 2MB
    float*          qbuf  = (float*)         (ws + (8ll  << 20));         // 8MB
    float*          abuf  = (float*)         (ws + (16ll << 20));         // 8MB
    unsigned short* kvbuf = (unsigned short*)(ws + (24ll << 20));         // 256MB

    // weight transpose+cast (K-major bf16)
    transpose_cast_kernel<<<dim3(1024 / 32, 1024 / 32), 256, 0, stream>>>(Wq,   WqT,   1024, 1024);
    transpose_cast_kernel<<<dim3(2048 / 32, 1024 / 32), 256, 0, stream>>>(Wkv,  WkvT,  1024, 2048);
    transpose_cast_kernel<<<dim3(1024 / 32, 1024 / 32), 256, 0, stream>>>(Wout, WoutT, 1024, 1024);

    // q = x @ Wq            [2048,1024] fp32
    gemm_kernel<<<dim3(2048 / 128, 1024 / 128), 256, 0, stream>>>(
        x, WqT, qbuf, nullptr, 2048, 1024, 1024, 0);
    // kv = context @ Wkv    [65536,2048] bf16
    gemm_kernel<<<dim3(65536 / 128, 2048 / 128), 256, 0, stream>>>(
        context, WkvT, kvbuf, nullptr, 65536, 2048, 1024, 1);
    // attention             [2048,1024] fp32
    attn_kernel<<<32768 / 4, 256, 0, stream>>>(qbuf, kvbuf, abuf);
    // out = attn @ Wout + bout   fp32
    gemm_kernel<<<dim3(2048 / 128, 1024 / 128), 256, 0, stream>>>(
        abuf, WoutT, out, bout, 2048, 1024, 1024, 0);
}

// Round 2
// 920.182 us; speedup vs baseline: 1.2234x; 1.2234x over previous
//
#include <hip/hip_runtime.h>
#include <hip/hip_bf16.h>

typedef __attribute__((ext_vector_type(8))) short short8;
typedef __attribute__((ext_vector_type(4))) float floatx4;

// ---------- helpers ----------
__device__ __forceinline__ unsigned short f32_to_bf16(float f) {
    unsigned int u = __builtin_bit_cast(unsigned int, f);
    u = (u + 0x7FFFu + ((u >> 16) & 1u)) >> 16;   // RNE
    return (unsigned short)u;
}
__device__ __forceinline__ unsigned int pack_bf16x2(float lo, float hi) {
    return (unsigned int)f32_to_bf16(lo) | ((unsigned int)f32_to_bf16(hi) << 16);
}
__device__ __forceinline__ float bf16_to_f32(unsigned short h) {
    unsigned int u = ((unsigned int)h) << 16;
    return __builtin_bit_cast(float, u);
}
// async global->LDS, 16B per lane; LDS dest = wave-uniform base + lane*16
__device__ __forceinline__ void async_load16(const unsigned short* g, unsigned short* l) {
    __builtin_amdgcn_global_load_lds(
        (const __attribute__((address_space(1))) void*)g,
        (__attribute__((address_space(3))) void*)l, 16, 0, 0);
}

// ---------- fp32 -> bf16 flat cast (n multiple of 2048) ----------
__global__ __launch_bounds__(256) void cast_bf16_kernel(
    const float* __restrict__ src, unsigned short* __restrict__ dst, long n) {
    long base = ((long)blockIdx.x * 256 + threadIdx.x) * 8;
    if (base >= n) return;
    float4 a = *(const float4*)(src + base);
    float4 b = *(const float4*)(src + base + 4);
    uint4 p;
    p.x = pack_bf16x2(a.x, a.y); p.y = pack_bf16x2(a.z, a.w);
    p.z = pack_bf16x2(b.x, b.y); p.w = pack_bf16x2(b.z, b.w);
    *(uint4*)(dst + base) = p;
}

// ---------- transpose + cast: W fp32 [K][N] -> Wt bf16 [N][K] ----------
__global__ __launch_bounds__(256) void transpose_cast_kernel(
    const float* __restrict__ W, unsigned short* __restrict__ Wt, int K, int N) {
    __shared__ float tile[32][33];
    int n0 = blockIdx.x * 32;
    int k0 = blockIdx.y * 32;
    int tx = threadIdx.x & 31;
    int ty = threadIdx.x >> 5;           // 0..7
#pragma unroll
    for (int p = 0; p < 4; ++p) {
        int r = ty + 8 * p;
        tile[r][tx] = W[(long)(k0 + r) * N + n0 + tx];
    }
    __syncthreads();
#pragma unroll
    for (int p = 0; p < 4; ++p) {
        int r = ty + 8 * p;
        Wt[(long)(n0 + r) * K + k0 + tx] = f32_to_bf16(tile[tx][r]);
    }
}

// ---------- GEMM: C[M,N] = A[M,K](bf16) @ Bt[N,K](bf16)^T ----------
// m97 structure: 128x128 tile, BK=32, 256 threads (4 waves), wave = 64x64
// via 4x4 of 16x16x32 bf16 MFMA. global_load_lds width-16 staging, LDS
// unpadded [128][32] (row stride 64B) as required by lane-sequential scatter.
__global__ __launch_bounds__(256) void gemm_bt_kernel(
    const unsigned short* __restrict__ A, const unsigned short* __restrict__ Bt,
    void* __restrict__ C, const float* __restrict__ bias,
    int M, int N, int K, int out_bf16) {
    __shared__ unsigned short As[128 * 32];
    __shared__ unsigned short Bs[128 * 32];

    const int tid  = threadIdx.x;
    const int wave = tid >> 6;
    const int lane = tid & 63;
    const int m0 = blockIdx.x * 128;
    const int n0 = blockIdx.y * 128;
    const int wrow = (wave >> 1) * 64;
    const int wcol = (wave & 1) * 64;

    floatx4 acc[4][4];
#pragma unroll
    for (int i = 0; i < 4; ++i)
#pragma unroll
        for (int j = 0; j < 4; ++j) acc[i][j] = (floatx4)0.0f;

    // staging map: wave w, issue i in {0,1}: LDS elem base w*1024 + i*512,
    // lane l lands 8 elems at row (w*32 + i*16 + (l>>2)), k-elems (l&3)*8.
    const int srow = wave * 32 + (lane >> 2);
    const int kofs = (lane & 3) * 8;
    const unsigned short* aAddr = A  + (long)(m0 + srow) * K + kofs;
    const unsigned short* bAddr = Bt + (long)(n0 + srow) * K + kofs;
    unsigned short* asBase = &As[wave * 1024];
    unsigned short* bsBase = &Bs[wave * 1024];

    const int frm = lane & 15;            // row within 16x16 tile
    const int fk  = (lane >> 4) * 8;      // k offset of this quad

    for (int kk = 0; kk < K; kk += 32) {
        __syncthreads();   // previous iter's ds_reads done before overwrite
        async_load16(aAddr + kk,              asBase);
        async_load16(aAddr + (long)16 * K + kk, asBase + 512);
        async_load16(bAddr + kk,              bsBase);
        async_load16(bAddr + (long)16 * K + kk, bsBase + 512);
        __syncthreads();   // drains vmcnt -> staging visible

        short8 afrag[4], bfrag[4];
#pragma unroll
        for (int rt = 0; rt < 4; ++rt)
            afrag[rt] = *(const short8*)&As[(wrow + rt * 16 + frm) * 32 + fk];
#pragma unroll
        for (int ct = 0; ct < 4; ++ct)
            bfrag[ct] = *(const short8*)&Bs[(wcol + ct * 16 + frm) * 32 + fk];
#pragma unroll
        for (int rt = 0; rt < 4; ++rt)
#pragma unroll
            for (int ct = 0; ct < 4; ++ct)
                acc[rt][ct] = __builtin_amdgcn_mfma_f32_16x16x32_bf16(
                    afrag[rt], bfrag[ct], acc[rt][ct], 0, 0, 0);
    }

    // epilogue: C/D layout col=lane&15, row=(lane>>4)*4+r
    const int orow0 = m0 + wrow + (lane >> 4) * 4;
    const int ocol0 = n0 + wcol + (lane & 15);
    if (out_bf16) {
        unsigned short* Cb = (unsigned short*)C;
#pragma unroll
        for (int rt = 0; rt < 4; ++rt)
#pragma unroll
            for (int r = 0; r < 4; ++r) {
                long row = orow0 + rt * 16 + r;
#pragma unroll
                for (int ct = 0; ct < 4; ++ct)
                    Cb[row * N + ocol0 + ct * 16] = f32_to_bf16(acc[rt][ct][r]);
            }
    } else {
        float* Cf = (float*)C;
#pragma unroll
        for (int rt = 0; rt < 4; ++rt)
#pragma unroll
            for (int r = 0; r < 4; ++r) {
                long row = orow0 + rt * 16 + r;
#pragma unroll
                for (int ct = 0; ct < 4; ++ct) {
                    int col = ocol0 + ct * 16;
                    float v = acc[rt][ct][r];
                    if (bias) v += bias[col];
                    Cf[row * N + col] = v;
                }
            }
    }
}

// ---------- attention: 1 wave per (b,h,i); 32 keys at j = i + 128t ----------
__global__ __launch_bounds__(256) void attn_kernel(
    const float* __restrict__ q,            // [2048,1024] fp32
    const unsigned short* __restrict__ kv,  // [65536,2048] bf16 (k: 0..1023, v: 1024..2047)
    unsigned short* __restrict__ attn) {    // [2048,1024] bf16
    const int wave = threadIdx.x >> 6;
    const int lane = threadIdx.x & 63;
    const int flat = blockIdx.x * 4 + wave;   // 0..32767
    const int b = flat >> 11;
    const int h = (flat >> 7) & 15;
    const int i = flat & 127;
    const int d = lane;

    const float qv = q[(long)(b * 128 + i) * 1024 + h * 64 + d];
    const float scale = 0.125f;   // 64^-0.5

    float vreg[32], sc[32];
#pragma unroll
    for (int t = 0; t < 32; ++t) {
        long base = ((long)b * 4096 + i + t * 128) * 2048 + h * 64;
        float kd = bf16_to_f32(kv[base + d]);
        vreg[t]  = bf16_to_f32(kv[base + 1024 + d]);
        float p = qv * kd;
#pragma unroll
        for (int off = 32; off > 0; off >>= 1) p += __shfl_xor(p, off, 64);
        sc[t] = p * scale;
    }
    float mx = sc[0];
#pragma unroll
    for (int t = 1; t < 32; ++t) mx = fmaxf(mx, sc[t]);
    float denom = 0.0f;
#pragma unroll
    for (int t = 0; t < 32; ++t) { sc[t] = __expf(sc[t] - mx); denom += sc[t]; }
    float inv = 1.0f / denom;
    float acc = 0.0f;
#pragma unroll
    for (int t = 0; t < 32; ++t) acc += sc[t] * vreg[t];
    attn[(long)(b * 128 + i) * 1024 + h * 64 + d] = f32_to_bf16(acc * inv);
}

// ---------- launch ----------
extern "C" void kernel_launch(void* const* d_in, const int* in_sizes, int n_in,
                              void* d_out, int out_size, void* d_ws, size_t ws_size,
                              hipStream_t stream) {
    const float* x       = (const float*)d_in[0];   // [16,128,1024]
    const float* context = (const float*)d_in[1];   // [16,4096,1024]
    const float* Wq      = (const float*)d_in[2];   // [1024,1024]
    const float* Wkv     = (const float*)d_in[3];   // [1024,2048]
    const float* Wout    = (const float*)d_in[4];   // [1024,1024]
    const float* bout    = (const float*)d_in[5];   // [1024]
    float* out = (float*)d_out;                     // [16,128,1024] fp32

    char* ws = (char*)d_ws;
    unsigned short* WqT   = (unsigned short*)(ws);                        // 2MB
    unsigned short* WkvT  = (unsigned short*)(ws + (2ll   << 20));        // 4MB
    unsigned short* WoutT = (unsigned short*)(ws + (6ll   << 20));        // 2MB
    unsigned short* xb    = (unsigned short*)(ws + (8ll   << 20));        // 4MB
    float*          qbuf  = (float*)         (ws + (12ll  << 20));        // 8MB
    unsigned short* abuf  = (unsigned short*)(ws + (20ll  << 20));        // 4MB
    unsigned short* ctxb  = (unsigned short*)(ws + (24ll  << 20));        // 128MB
    unsigned short* kvbuf = (unsigned short*)(ws + (152ll << 20));        // 256MB

    // input casts to bf16
    cast_bf16_kernel<<<1024, 256, 0, stream>>>(x, xb, 2097152L);
    cast_bf16_kernel<<<32768, 256, 0, stream>>>(context, ctxb, 67108864L);

    // weight transpose+cast (K-major bf16)
    transpose_cast_kernel<<<dim3(1024 / 32, 1024 / 32), 256, 0, stream>>>(Wq,   WqT,   1024, 1024);
    transpose_cast_kernel<<<dim3(2048 / 32, 1024 / 32), 256, 0, stream>>>(Wkv,  WkvT,  1024, 2048);
    transpose_cast_kernel<<<dim3(1024 / 32, 1024 / 32), 256, 0, stream>>>(Wout, WoutT, 1024, 1024);

    // q = x @ Wq            [2048,1024] fp32
    gemm_bt_kernel<<<dim3(2048 / 128, 1024 / 128), 256, 0, stream>>>(
        xb, WqT, qbuf, nullptr, 2048, 1024, 1024, 0);
    // kv = context @ Wkv    [65536,2048] bf16
    gemm_bt_kernel<<<dim3(65536 / 128, 2048 / 128), 256, 0, stream>>>(
        ctxb, WkvT, kvbuf, nullptr, 65536, 2048, 1024, 1);
    // attention             [2048,1024] bf16
    attn_kernel<<<32768 / 4, 256, 0, stream>>>(qbuf, kvbuf, abuf);
    // out = attn @ Wout + bout   fp32
    gemm_bt_kernel<<<dim3(2048 / 128, 1024 / 128), 256, 0, stream>>>(
        abuf, WoutT, out, bout, 2048, 1024, 1024, 0);
}

// Round 3
// 918.564 us; speedup vs baseline: 1.2255x; 1.0018x over previous
//
#include <hip/hip_runtime.h>
#include <hip/hip_bf16.h>

typedef __attribute__((ext_vector_type(8))) short short8;
typedef __attribute__((ext_vector_type(4))) float floatx4;

// ---------- helpers ----------
__device__ __forceinline__ unsigned short f32_to_bf16(float f) {
    unsigned int u = __builtin_bit_cast(unsigned int, f);
    u = (u + 0x7FFFu + ((u >> 16) & 1u)) >> 16;   // RNE
    return (unsigned short)u;
}
__device__ __forceinline__ unsigned int pack_bf16x2(float lo, float hi) {
    return (unsigned int)f32_to_bf16(lo) | ((unsigned int)f32_to_bf16(hi) << 16);
}
__device__ __forceinline__ float bf16_to_f32(unsigned short h) {
    unsigned int u = ((unsigned int)h) << 16;
    return __builtin_bit_cast(float, u);
}
// async global->LDS, 16B per lane; LDS dest = wave-uniform base + lane*16
__device__ __forceinline__ void async_load16(const unsigned short* g, unsigned short* l) {
    __builtin_amdgcn_global_load_lds(
        (const __attribute__((address_space(1))) void*)g,
        (__attribute__((address_space(3))) void*)l, 16, 0, 0);
}

// ---------- transpose tile helper: W fp32 [K][N] -> Wt bf16 [N][K], 32x32 ----------
__device__ __forceinline__ void transpose_tile(
    const float* __restrict__ W, unsigned short* __restrict__ Wt,
    int K, int N, int nb, int kb, int tid) {
    __shared__ float tile[32][33];
    int n0 = nb * 32;
    int k0 = kb * 32;
    int tx = tid & 31;
    int ty = tid >> 5;           // 0..7
#pragma unroll
    for (int p = 0; p < 4; ++p) {
        int r = ty + 8 * p;
        tile[r][tx] = W[(long)(k0 + r) * N + n0 + tx];
    }
    __syncthreads();
#pragma unroll
    for (int p = 0; p < 4; ++p) {
        int r = ty + 8 * p;
        Wt[(long)(n0 + r) * K + k0 + tx] = f32_to_bf16(tile[tx][r]);
    }
}

__device__ __forceinline__ void flat_cast8(
    const float* __restrict__ src, unsigned short* __restrict__ dst, long base) {
    float4 a = *(const float4*)(src + base);
    float4 b = *(const float4*)(src + base + 4);
    uint4 p;
    p.x = pack_bf16x2(a.x, a.y); p.y = pack_bf16x2(a.z, a.w);
    p.z = pack_bf16x2(b.x, b.y); p.w = pack_bf16x2(b.z, b.w);
    *(uint4*)(dst + base) = p;
}

// ---------- fused prep: 3 weight transposes + x cast + context cast ----------
// block ranges: [0,1024) WqT | [1024,3072) WkvT | [3072,4096) WoutT |
//               [4096,5120) x cast | [5120,37888) context cast
__global__ __launch_bounds__(256) void prep_kernel(
    const float* __restrict__ Wq, const float* __restrict__ Wkv,
    const float* __restrict__ Wout, const float* __restrict__ x,
    const float* __restrict__ ctx,
    unsigned short* __restrict__ WqT, unsigned short* __restrict__ WkvT,
    unsigned short* __restrict__ WoutT, unsigned short* __restrict__ xb,
    unsigned short* __restrict__ ctxb) {
    int id = blockIdx.x;
    int tid = threadIdx.x;
    if (id < 1024) { transpose_tile(Wq, WqT, 1024, 1024, id & 31, id >> 5, tid); return; }
    id -= 1024;
    if (id < 2048) { transpose_tile(Wkv, WkvT, 1024, 2048, id & 63, id >> 6, tid); return; }
    id -= 2048;
    if (id < 1024) { transpose_tile(Wout, WoutT, 1024, 1024, id & 31, id >> 5, tid); return; }
    id -= 1024;
    if (id < 1024) { flat_cast8(x, xb, ((long)id * 256 + tid) * 8); return; }
    id -= 1024;
    flat_cast8(ctx, ctxb, ((long)id * 256 + tid) * 8);
}

// ---------- GEMM: C[M,N] = A[M,K](bf16) @ Bt[N,K](bf16)^T ----------
// m97 structure: 128x128 tile, BK=32, 256 threads (4 waves), wave = 64x64
// via 4x4 of 16x16x32 bf16 MFMA. global_load_lds width-16 staging, LDS
// unpadded [128][32]. Grid: x = N-blocks (fast) so consecutive blocks share
// the same A-tile -> A fetched from HBM once, B stays L2/L3-resident.
__global__ __launch_bounds__(256) void gemm_bt_kernel(
    const unsigned short* __restrict__ A, const unsigned short* __restrict__ Bt,
    void* __restrict__ C, const float* __restrict__ bias,
    int M, int N, int K, int out_bf16) {
    __shared__ unsigned short As[128 * 32];
    __shared__ unsigned short Bs[128 * 32];

    const int tid  = threadIdx.x;
    const int wave = tid >> 6;
    const int lane = tid & 63;
    const int m0 = blockIdx.y * 128;   // M on y (slow)
    const int n0 = blockIdx.x * 128;   // N on x (fast) -> A-tile reuse
    const int wrow = (wave >> 1) * 64;
    const int wcol = (wave & 1) * 64;

    floatx4 acc[4][4];
#pragma unroll
    for (int i = 0; i < 4; ++i)
#pragma unroll
        for (int j = 0; j < 4; ++j) acc[i][j] = (floatx4)0.0f;

    // staging map: wave w, issue i in {0,1}: LDS elem base w*1024 + i*512,
    // lane l lands 8 elems at row (w*32 + i*16 + (l>>2)), k-elems (l&3)*8.
    const int srow = wave * 32 + (lane >> 2);
    const int kofs = (lane & 3) * 8;
    const unsigned short* aAddr = A  + (long)(m0 + srow) * K + kofs;
    const unsigned short* bAddr = Bt + (long)(n0 + srow) * K + kofs;
    unsigned short* asBase = &As[wave * 1024];
    unsigned short* bsBase = &Bs[wave * 1024];

    const int frm = lane & 15;            // row within 16x16 tile
    const int fk  = (lane >> 4) * 8;      // k offset of this quad

    for (int kk = 0; kk < K; kk += 32) {
        __syncthreads();   // previous iter's ds_reads done before overwrite
        async_load16(aAddr + kk,                asBase);
        async_load16(aAddr + (long)16 * K + kk, asBase + 512);
        async_load16(bAddr + kk,                bsBase);
        async_load16(bAddr + (long)16 * K + kk, bsBase + 512);
        __syncthreads();   // drains vmcnt -> staging visible

        short8 afrag[4], bfrag[4];
#pragma unroll
        for (int rt = 0; rt < 4; ++rt)
            afrag[rt] = *(const short8*)&As[(wrow + rt * 16 + frm) * 32 + fk];
#pragma unroll
        for (int ct = 0; ct < 4; ++ct)
            bfrag[ct] = *(const short8*)&Bs[(wcol + ct * 16 + frm) * 32 + fk];
#pragma unroll
        for (int rt = 0; rt < 4; ++rt)
#pragma unroll
            for (int ct = 0; ct < 4; ++ct)
                acc[rt][ct] = __builtin_amdgcn_mfma_f32_16x16x32_bf16(
                    afrag[rt], bfrag[ct], acc[rt][ct], 0, 0, 0);
    }

    // epilogue: C/D layout col=lane&15, row=(lane>>4)*4+r
    const int orow0 = m0 + wrow + (lane >> 4) * 4;
    const int ocol0 = n0 + wcol + (lane & 15);
    if (out_bf16) {
        unsigned short* Cb = (unsigned short*)C;
#pragma unroll
        for (int rt = 0; rt < 4; ++rt)
#pragma unroll
            for (int r = 0; r < 4; ++r) {
                long row = orow0 + rt * 16 + r;
#pragma unroll
                for (int ct = 0; ct < 4; ++ct)
                    Cb[row * N + ocol0 + ct * 16] = f32_to_bf16(acc[rt][ct][r]);
            }
    } else {
        float* Cf = (float*)C;
#pragma unroll
        for (int rt = 0; rt < 4; ++rt)
#pragma unroll
            for (int r = 0; r < 4; ++r) {
                long row = orow0 + rt * 16 + r;
#pragma unroll
                for (int ct = 0; ct < 4; ++ct) {
                    int col = ocol0 + ct * 16;
                    float v = acc[rt][ct][r];
                    if (bias) v += bias[col];
                    Cf[row * N + col] = v;
                }
            }
    }
}

// ---------- attention: 1 wave per (b,h,i); 32 keys at j = i + 128t ----------
__global__ __launch_bounds__(256) void attn_kernel(
    const float* __restrict__ q,            // [2048,1024] fp32
    const unsigned short* __restrict__ kv,  // [65536,2048] bf16 (k: 0..1023, v: 1024..2047)
    unsigned short* __restrict__ attn) {    // [2048,1024] bf16
    const int wave = threadIdx.x >> 6;
    const int lane = threadIdx.x & 63;
    const int flat = blockIdx.x * 4 + wave;   // 0..32767
    const int b = flat >> 11;
    const int h = (flat >> 7) & 15;
    const int i = flat & 127;
    const int d = lane;

    const float qv = q[(long)(b * 128 + i) * 1024 + h * 64 + d];
    const float scale = 0.125f;   // 64^-0.5

    float vreg[32], sc[32];
#pragma unroll
    for (int t = 0; t < 32; ++t) {
        long base = ((long)b * 4096 + i + t * 128) * 2048 + h * 64;
        float kd = bf16_to_f32(kv[base + d]);
        vreg[t]  = bf16_to_f32(kv[base + 1024 + d]);
        float p = qv * kd;
#pragma unroll
        for (int off = 32; off > 0; off >>= 1) p += __shfl_xor(p, off, 64);
        sc[t] = p * scale;
    }
    float mx = sc[0];
#pragma unroll
    for (int t = 1; t < 32; ++t) mx = fmaxf(mx, sc[t]);
    float denom = 0.0f;
#pragma unroll
    for (int t = 0; t < 32; ++t) { sc[t] = __expf(sc[t] - mx); denom += sc[t]; }
    float inv = 1.0f / denom;
    float acc = 0.0f;
#pragma unroll
    for (int t = 0; t < 32; ++t) acc += sc[t] * vreg[t];
    attn[(long)(b * 128 + i) * 1024 + h * 64 + d] = f32_to_bf16(acc * inv);
}

// ---------- launch ----------
extern "C" void kernel_launch(void* const* d_in, const int* in_sizes, int n_in,
                              void* d_out, int out_size, void* d_ws, size_t ws_size,
                              hipStream_t stream) {
    const float* x       = (const float*)d_in[0];   // [16,128,1024]
    const float* context = (const float*)d_in[1];   // [16,4096,1024]
    const float* Wq      = (const float*)d_in[2];   // [1024,1024]
    const float* Wkv     = (const float*)d_in[3];   // [1024,2048]
    const float* Wout    = (const float*)d_in[4];   // [1024,1024]
    const float* bout    = (const float*)d_in[5];   // [1024]
    float* out = (float*)d_out;                     // [16,128,1024] fp32

    char* ws = (char*)d_ws;
    unsigned short* WqT   = (unsigned short*)(ws);                        // 2MB
    unsigned short* WkvT  = (unsigned short*)(ws + (2ll   << 20));        // 4MB
    unsigned short* WoutT = (unsigned short*)(ws + (6ll   << 20));        // 2MB
    unsigned short* xb    = (unsigned short*)(ws + (8ll   << 20));        // 4MB
    float*          qbuf  = (float*)         (ws + (12ll  << 20));        // 8MB
    unsigned short* abuf  = (unsigned short*)(ws + (20ll  << 20));        // 4MB
    unsigned short* ctxb  = (unsigned short*)(ws + (24ll  << 20));        // 128MB
    unsigned short* kvbuf = (unsigned short*)(ws + (152ll << 20));        // 256MB

    // fused prep: weight transposes + input casts (one launch)
    prep_kernel<<<37888, 256, 0, stream>>>(
        Wq, Wkv, Wout, x, context, WqT, WkvT, WoutT, xb, ctxb);

    // q = x @ Wq            [2048,1024] fp32
    gemm_bt_kernel<<<dim3(1024 / 128, 2048 / 128), 256, 0, stream>>>(
        xb, WqT, qbuf, nullptr, 2048, 1024, 1024, 0);
    // kv = context @ Wkv    [65536,2048] bf16
    gemm_bt_kernel<<<dim3(2048 / 128, 65536 / 128), 256, 0, stream>>>(
        ctxb, WkvT, kvbuf, nullptr, 65536, 2048, 1024, 1);
    // attention             [2048,1024] bf16
    attn_kernel<<<32768 / 4, 256, 0, stream>>>(qbuf, kvbuf, abuf);
    // out = attn @ Wout + bout   fp32
    gemm_bt_kernel<<<dim3(1024 / 128, 2048 / 128), 256, 0, stream>>>(
        abuf, WoutT, out, bout, 2048, 1024, 1024, 0);
}

// Round 4
// 501.118 us; speedup vs baseline: 2.2464x; 1.8330x over previous
//
#include <hip/hip_runtime.h>
#include <hip/hip_bf16.h>

typedef __attribute__((ext_vector_type(8))) short short8;
typedef __attribute__((ext_vector_type(4))) float floatx4;

// ---------- helpers ----------
__device__ __forceinline__ unsigned short f32_to_bf16(float f) {
    unsigned int u = __builtin_bit_cast(unsigned int, f);
    u = (u + 0x7FFFu + ((u >> 16) & 1u)) >> 16;   // RNE
    return (unsigned short)u;
}
__device__ __forceinline__ unsigned int pack_bf16x2(float lo, float hi) {
    return (unsigned int)f32_to_bf16(lo) | ((unsigned int)f32_to_bf16(hi) << 16);
}
// async global->LDS, 16B per lane; LDS dest = wave-uniform base + lane*16
__device__ __forceinline__ void async_load16(const unsigned short* g, unsigned short* l) {
    __builtin_amdgcn_global_load_lds(
        (const __attribute__((address_space(1))) void*)g,
        (__attribute__((address_space(3))) void*)l, 16, 0, 0);
}

// ---------- transpose tile: Wt[n][k] = W[k][n_off+n], 32x32 ----------
__device__ __forceinline__ void transpose_tile(
    const float* __restrict__ W, int src_ld, int n_off,
    unsigned short* __restrict__ Wt, int dst_ld, int nb, int kb, int tid) {
    __shared__ float tile[32][33];
    int n0 = nb * 32, k0 = kb * 32;
    int tx = tid & 31, ty = tid >> 5;    // ty 0..7
#pragma unroll
    for (int p = 0; p < 4; ++p) {
        int r = ty + 8 * p;
        tile[r][tx] = W[(long)(k0 + r) * src_ld + n_off + n0 + tx];
    }
    __syncthreads();
#pragma unroll
    for (int p = 0; p < 4; ++p) {
        int r = ty + 8 * p;
        Wt[(long)(n0 + r) * dst_ld + k0 + tx] = f32_to_bf16(tile[tx][r]);
    }
}

__device__ __forceinline__ void cast8(
    const float* __restrict__ src, unsigned short* __restrict__ dst) {
    float4 a = *(const float4*)src;
    float4 b = *(const float4*)(src + 4);
    uint4 p;
    p.x = pack_bf16x2(a.x, a.y); p.y = pack_bf16x2(a.z, a.w);
    p.z = pack_bf16x2(b.x, b.y); p.w = pack_bf16x2(b.z, b.w);
    *(uint4*)dst = p;
}

// ---------- fused prep ----------
// blocks: [0,1024) WqT | [1024,2048) WvT | [2048,3072) WoutT |
//         [3072,3584) WkB strided cast | [3584,4608) x cast
__global__ __launch_bounds__(256) void prep_kernel(
    const float* __restrict__ Wq, const float* __restrict__ Wkv,
    const float* __restrict__ Wout, const float* __restrict__ x,
    unsigned short* __restrict__ WqT, unsigned short* __restrict__ WkB,
    unsigned short* __restrict__ WvT, unsigned short* __restrict__ WoutT,
    unsigned short* __restrict__ xb) {
    int id = blockIdx.x, tid = threadIdx.x;
    if (id < 1024) { transpose_tile(Wq,   1024, 0,    WqT,   1024, id & 31, id >> 5, tid); return; }
    id -= 1024;
    if (id < 1024) { transpose_tile(Wkv,  2048, 1024, WvT,   1024, id & 31, id >> 5, tid); return; }
    id -= 1024;
    if (id < 1024) { transpose_tile(Wout, 1024, 0,    WoutT, 1024, id & 31, id >> 5, tid); return; }
    id -= 1024;
    if (id < 512) {   // WkB[c][d] = bf16(Wkv[c][d]), d<1024
        long e = ((long)id * 256 + tid) * 8;
        long row = e >> 10, col = e & 1023;
        cast8(Wkv + row * 2048 + col, WkB + e);
        return;
    }
    id -= 512;
    { long e = ((long)id * 256 + tid) * 8; cast8(x + e, xb + e); }
}

// ---------- GEMM: C[.,N] = A[.,K](bf16) @ Bt[N,K](bf16)^T, 128x128 tile ----------
// m97 structure; batched via blockIdx.z with element strides sA/sB/sC.
__global__ __launch_bounds__(256, 2) void gemm_bt_kernel(
    const unsigned short* __restrict__ A, long sA, int lda,
    const unsigned short* __restrict__ Bt, long sB, int ldb,
    void* __restrict__ C, long sC, int ldc,
    const float* __restrict__ bias, int K, int out_bf16) {
    __shared__ unsigned short As[128 * 32];
    __shared__ unsigned short Bs[128 * 32];

    const int tid = threadIdx.x, wave = tid >> 6, lane = tid & 63;
    const int z = blockIdx.z;
    A  += (long)z * sA;
    Bt += (long)z * sB;
    const int m0 = blockIdx.y * 128, n0 = blockIdx.x * 128;
    const int wrow = (wave >> 1) * 64, wcol = (wave & 1) * 64;

    floatx4 acc[4][4];
#pragma unroll
    for (int i = 0; i < 4; ++i)
#pragma unroll
        for (int j = 0; j < 4; ++j) acc[i][j] = (floatx4)0.0f;

    const int srow = wave * 32 + (lane >> 2);
    const int kofs = (lane & 3) * 8;
    const unsigned short* aAddr = A  + (long)(m0 + srow) * lda + kofs;
    const unsigned short* bAddr = Bt + (long)(n0 + srow) * ldb + kofs;
    unsigned short* asBase = &As[wave * 1024];
    unsigned short* bsBase = &Bs[wave * 1024];

    const int frm = lane & 15, fk = (lane >> 4) * 8;

    for (int kk = 0; kk < K; kk += 32) {
        __syncthreads();
        async_load16(aAddr + kk,                  asBase);
        async_load16(aAddr + (long)16 * lda + kk, asBase + 512);
        async_load16(bAddr + kk,                  bsBase);
        async_load16(bAddr + (long)16 * ldb + kk, bsBase + 512);
        __syncthreads();

        short8 afrag[4], bfrag[4];
#pragma unroll
        for (int rt = 0; rt < 4; ++rt)
            afrag[rt] = *(const short8*)&As[(wrow + rt * 16 + frm) * 32 + fk];
#pragma unroll
        for (int ct = 0; ct < 4; ++ct)
            bfrag[ct] = *(const short8*)&Bs[(wcol + ct * 16 + frm) * 32 + fk];
#pragma unroll
        for (int rt = 0; rt < 4; ++rt)
#pragma unroll
            for (int ct = 0; ct < 4; ++ct)
                acc[rt][ct] = __builtin_amdgcn_mfma_f32_16x16x32_bf16(
                    afrag[rt], bfrag[ct], acc[rt][ct], 0, 0, 0);
    }

    const int orow0 = m0 + wrow + (lane >> 4) * 4;
    const int ocol0 = n0 + wcol + (lane & 15);
    if (out_bf16) {
        unsigned short* Cb = (unsigned short*)C + (long)z * sC;
#pragma unroll
        for (int rt = 0; rt < 4; ++rt)
#pragma unroll
            for (int r = 0; r < 4; ++r) {
                long row = orow0 + rt * 16 + r;
#pragma unroll
                for (int ct = 0; ct < 4; ++ct)
                    Cb[row * ldc + ocol0 + ct * 16] = f32_to_bf16(acc[rt][ct][r]);
            }
    } else {
        float* Cf = (float*)C + (long)z * sC;
#pragma unroll
        for (int rt = 0; rt < 4; ++rt)
#pragma unroll
            for (int r = 0; r < 4; ++r) {
                long row = orow0 + rt * 16 + r;
#pragma unroll
                for (int ct = 0; ct < 4; ++ct) {
                    int col = ocol0 + ct * 16;
                    float v = acc[rt][ct][r];
                    if (bias) v += bias[col];
                    Cf[row * ldc + col] = v;
                }
            }
    }
}

// ---------- GEMM variant: BM=256, BN=64 (v-apply), 4 waves stacked on M ----------
__global__ __launch_bounds__(256, 2) void gemm_n64_kernel(
    const unsigned short* __restrict__ A, long sA, int lda,
    const unsigned short* __restrict__ Bt, long sB, int ldb,
    unsigned short* __restrict__ C, long sC, int ldc, int K) {
    __shared__ unsigned short As[256 * 32];   // 16 KB
    __shared__ unsigned short Bs[64 * 32];    // 4 KB

    const int tid = threadIdx.x, wave = tid >> 6, lane = tid & 63;
    const int z = blockIdx.z;
    A  += (long)z * sA;
    Bt += (long)z * sB;
    C  += (long)z * sC;
    const int m0 = blockIdx.y * 256;

    floatx4 acc[4][4];
#pragma unroll
    for (int i = 0; i < 4; ++i)
#pragma unroll
        for (int j = 0; j < 4; ++j) acc[i][j] = (floatx4)0.0f;

    const int srow = tid >> 2;            // 0..63
    const int kofs = (tid & 3) * 8;
    const unsigned short* aBase = A  + (long)(m0 + srow) * lda + kofs;
    const unsigned short* bAddr = Bt + (long)srow * ldb + kofs;
    unsigned short* asW = &As[wave * 512];
    unsigned short* bsW = &Bs[wave * 512];

    const int frm = lane & 15, fk = (lane >> 4) * 8;

    for (int kk = 0; kk < K; kk += 32) {
        __syncthreads();
        async_load16(aBase + kk,                   asW);
        async_load16(aBase + (long)64  * lda + kk, asW + 2048);
        async_load16(aBase + (long)128 * lda + kk, asW + 4096);
        async_load16(aBase + (long)192 * lda + kk, asW + 6144);
        async_load16(bAddr + kk,                   bsW);
        __syncthreads();

        short8 afrag[4], bfrag[4];
#pragma unroll
        for (int rt = 0; rt < 4; ++rt)
            afrag[rt] = *(const short8*)&As[(wave * 64 + rt * 16 + frm) * 32 + fk];
#pragma unroll
        for (int ct = 0; ct < 4; ++ct)
            bfrag[ct] = *(const short8*)&Bs[(ct * 16 + frm) * 32 + fk];
#pragma unroll
        for (int rt = 0; rt < 4; ++rt)
#pragma unroll
            for (int ct = 0; ct < 4; ++ct)
                acc[rt][ct] = __builtin_amdgcn_mfma_f32_16x16x32_bf16(
                    afrag[rt], bfrag[ct], acc[rt][ct], 0, 0, 0);
    }

    const int orow0 = m0 + wave * 64 + (lane >> 4) * 4;
    const int ocol0 = lane & 15;
#pragma unroll
    for (int rt = 0; rt < 4; ++rt)
#pragma unroll
        for (int r = 0; r < 4; ++r) {
            long row = orow0 + rt * 16 + r;
#pragma unroll
            for (int ct = 0; ct < 4; ++ct)
                C[row * ldc + ocol0 + ct * 16] = f32_to_bf16(acc[rt][ct][r]);
        }
}

// ---------- fused attention: s = qt.ctx^T -> softmax -> wctx = p.ctx ----------
// one block per (b,i); 32 ctx rows j=i+128t loaded once (fp32->bf16 LDS).
// s-MFMA: A=qt[16h][1024c], B=ctx[32t][1024c] (both row-major, no transpose).
// wctx-MFMA: A=p[16h][32t] (LDS round-trip), B=ctx^T via strided u16 gather.
#define CLD 1032   // LDS row stride (elems) for qt/ctx: breaks b128 bank aliasing
__global__ __launch_bounds__(256) void attn_fused_kernel(
    const float* __restrict__ ctx,          // fp32 [16*4096][1024]
    const unsigned short* __restrict__ qt,  // bf16 16 slabs of [2048][1024]
    unsigned short* __restrict__ wctx) {    // bf16 16 slabs of [2048][1024]
    __shared__ unsigned short ctx_t[32 * CLD];   // 66 KB
    __shared__ unsigned short qt_t[16 * CLD];    // 33 KB
    __shared__ float sred[4 * 512];              // 8 KB
    __shared__ float s_f[512];                   // 2 KB
    __shared__ float mxs[16], inv_[16];
    __shared__ unsigned short p_l[16 * 40];      // p in A-layout [h][t], padded

    const int tid = threadIdx.x, wave = tid >> 6, lane = tid & 63;
    const int bi = blockIdx.x;
    const int b = bi >> 7, i = bi & 127;
    const int frm = lane & 15, fk = (lane >> 4) * 8;

    // load qt rows (16 x 1024 bf16)
#pragma unroll
    for (int rr = 0; rr < 8; ++rr) {
        int idx = rr * 2048 + tid * 8;
        int h = idx >> 10, c = idx & 1023;
        *(uint4*)&qt_t[h * CLD + c] =
            *(const uint4*)&qt[(long)h * 2048 * 1024 + (long)bi * 1024 + c];
    }
    // load ctx rows j=i+128t (fp32 -> bf16)
#pragma unroll
    for (int rr = 0; rr < 16; ++rr) {
        int idx = rr * 2048 + tid * 8;
        int t = idx >> 10, c = idx & 1023;
        cast8(ctx + ((long)b * 4096 + i + t * 128) * 1024 + c, &ctx_t[t * CLD + c]);
    }
    __syncthreads();

    // s partials: wave w covers k in [w*256, w*256+256)
    floatx4 acc0 = (floatx4)0.0f, acc1 = (floatx4)0.0f;
#pragma unroll
    for (int it = 0; it < 8; ++it) {
        int kk = wave * 256 + it * 32;
        short8 af = *(const short8*)&qt_t[frm * CLD + kk + fk];
        short8 b0 = *(const short8*)&ctx_t[frm * CLD + kk + fk];
        short8 b1 = *(const short8*)&ctx_t[(16 + frm) * CLD + kk + fk];
        acc0 = __builtin_amdgcn_mfma_f32_16x16x32_bf16(af, b0, acc0, 0, 0, 0);
        acc1 = __builtin_amdgcn_mfma_f32_16x16x32_bf16(af, b1, acc1, 0, 0, 0);
    }
    // C-layout: t = lane&15 (+16 for acc1), h = (lane>>4)*4 + r; store sred[t*16+h]
#pragma unroll
    for (int r = 0; r < 4; ++r) {
        sred[wave * 512 + frm * 16 + (lane >> 4) * 4 + r]        = acc0[r];
        sred[wave * 512 + (16 + frm) * 16 + (lane >> 4) * 4 + r] = acc1[r];
    }
    __syncthreads();
    // cross-wave reduce + scale
#pragma unroll
    for (int half = 0; half < 2; ++half) {
        int idx = half * 256 + tid;
        s_f[idx] = (sred[idx] + sred[512 + idx] + sred[1024 + idx] + sred[1536 + idx]) * 0.125f;
    }
    __syncthreads();
    // softmax over t (32) per h
    if (tid < 16) {
        int h = tid;
        float m = -1e30f;
        for (int t = 0; t < 32; ++t) m = fmaxf(m, s_f[t * 16 + h]);
        float den = 0.0f;
        for (int t = 0; t < 32; ++t) den += __expf(s_f[t * 16 + h] - m);
        mxs[h] = m; inv_[h] = 1.0f / den;
    }
    __syncthreads();
#pragma unroll
    for (int half = 0; half < 2; ++half) {
        int idx = half * 256 + tid;
        int t = idx >> 4, h = idx & 15;
        p_l[h * 40 + t] = f32_to_bf16(__expf(s_f[idx] - mxs[h]) * inv_[h]);
    }
    __syncthreads();

    // wctx[h][c] = sum_t p[h][t] * ctx[t][c]; wave covers c-range wave*256
    short8 ap;
#pragma unroll
    for (int j = 0; j < 8; ++j) ap[j] = (short)p_l[frm * 40 + fk + j];
#pragma unroll 4
    for (int nt = 0; nt < 16; ++nt) {
        int c0 = wave * 256 + nt * 16;
        short8 bt;
#pragma unroll
        for (int j = 0; j < 8; ++j) bt[j] = (short)ctx_t[(fk + j) * CLD + c0 + frm];
        floatx4 wacc = __builtin_amdgcn_mfma_f32_16x16x32_bf16(ap, bt, (floatx4)0.0f, 0, 0, 0);
#pragma unroll
        for (int r = 0; r < 4; ++r) {
            int h = (lane >> 4) * 4 + r;
            wctx[(long)h * 2048 * 1024 + (long)bi * 1024 + c0 + frm] = f32_to_bf16(wacc[r]);
        }
    }
}

// ---------- launch ----------
extern "C" void kernel_launch(void* const* d_in, const int* in_sizes, int n_in,
                              void* d_out, int out_size, void* d_ws, size_t ws_size,
                              hipStream_t stream) {
    const float* x       = (const float*)d_in[0];   // [16,128,1024]
    const float* context = (const float*)d_in[1];   // [16,4096,1024]
    const float* Wq      = (const float*)d_in[2];   // [1024,1024]
    const float* Wkv     = (const float*)d_in[3];   // [1024,2048]
    const float* Wout    = (const float*)d_in[4];   // [1024,1024]
    const float* bout    = (const float*)d_in[5];   // [1024]
    float* out = (float*)d_out;                     // [16,128,1024] fp32

    char* ws = (char*)d_ws;
    unsigned short* WqT   = (unsigned short*)(ws);                       // 2MB
    unsigned short* WkB   = (unsigned short*)(ws + (2ll  << 20));        // 2MB (k-half of Wkv, bf16)
    unsigned short* WvT   = (unsigned short*)(ws + (4ll  << 20));        // 2MB (v-half, transposed)
    unsigned short* WoutT = (unsigned short*)(ws + (6ll  << 20));        // 2MB
    unsigned short* xb    = (unsigned short*)(ws + (8ll  << 20));        // 4MB
    unsigned short* qb    = (unsigned short*)(ws + (12ll << 20));        // 4MB
    unsigned short* aob   = (unsigned short*)(ws + (16ll << 20));        // 4MB
    unsigned short* qtb   = (unsigned short*)(ws + (32ll << 20));        // 64MB, 16 slabs [2048][1024]
    unsigned short* wctxb = (unsigned short*)(ws + (96ll << 20));        // 64MB, 16 slabs

    // prep: weight transposes/casts + x cast
    prep_kernel<<<4608, 256, 0, stream>>>(Wq, Wkv, Wout, x, WqT, WkB, WvT, WoutT, xb);

    // q = x @ Wq                       [2048,1024] bf16
    gemm_bt_kernel<<<dim3(8, 16, 1), 256, 0, stream>>>(
        xb, 0, 1024, WqT, 0, 1024, qb, 0, 1024, nullptr, 1024, 1);
    // qt[h] = q_h @ Wk_h^T             16 x [2048,1024] bf16  (K=64 per head)
    gemm_bt_kernel<<<dim3(8, 16, 16), 256, 0, stream>>>(
        qb, 64, 1024, WkB, 64, 1024, qtb, (long)2048 * 1024, 1024, nullptr, 64, 1);
    // fused: s -> softmax -> wctx      16 x [2048,1024] bf16
    attn_fused_kernel<<<2048, 256, 0, stream>>>(context, qtb, wctxb);
    // attn_out[:, h*64:..] = wctx_h @ Wv_h   [2048,1024] bf16
    gemm_n64_kernel<<<dim3(1, 8, 16), 256, 0, stream>>>(
        wctxb, (long)2048 * 1024, 1024, WvT, (long)64 * 1024, 1024, aob, 64, 1024, 1024);
    // out = attn_out @ Wout + bout     [2048,1024] fp32
    gemm_bt_kernel<<<dim3(8, 16, 1), 256, 0, stream>>>(
        aob, 0, 1024, WoutT, 0, 1024, out, 0, 1024, bout, 1024, 0);
}

// Round 5
// 478.905 us; speedup vs baseline: 2.3506x; 1.0464x over previous
//
#include <hip/hip_runtime.h>
#include <hip/hip_bf16.h>

typedef __attribute__((ext_vector_type(8))) short short8;
typedef __attribute__((ext_vector_type(4))) float floatx4;

// ---------- helpers ----------
__device__ __forceinline__ unsigned short f32_to_bf16(float f) {
    unsigned int u = __builtin_bit_cast(unsigned int, f);
    u = (u + 0x7FFFu + ((u >> 16) & 1u)) >> 16;   // RNE
    return (unsigned short)u;
}
__device__ __forceinline__ unsigned int pack_bf16x2(float lo, float hi) {
    return (unsigned int)f32_to_bf16(lo) | ((unsigned int)f32_to_bf16(hi) << 16);
}
// async global->LDS, 16B per lane; LDS dest = wave-uniform base + lane*16
__device__ __forceinline__ void async_load16(const unsigned short* g, unsigned short* l) {
    __builtin_amdgcn_global_load_lds(
        (const __attribute__((address_space(1))) void*)g,
        (__attribute__((address_space(3))) void*)l, 16, 0, 0);
}

// ---------- transpose tile: Wt[n][k] = W[k][n_off+n], 32x32 ----------
__device__ __forceinline__ void transpose_tile(
    const float* __restrict__ W, int src_ld, int n_off,
    unsigned short* __restrict__ Wt, int dst_ld, int nb, int kb, int tid) {
    __shared__ float tile[32][33];
    int n0 = nb * 32, k0 = kb * 32;
    int tx = tid & 31, ty = tid >> 5;    // ty 0..7
#pragma unroll
    for (int p = 0; p < 4; ++p) {
        int r = ty + 8 * p;
        tile[r][tx] = W[(long)(k0 + r) * src_ld + n_off + n0 + tx];
    }
    __syncthreads();
#pragma unroll
    for (int p = 0; p < 4; ++p) {
        int r = ty + 8 * p;
        Wt[(long)(n0 + r) * dst_ld + k0 + tx] = f32_to_bf16(tile[tx][r]);
    }
}

__device__ __forceinline__ void cast8(
    const float* __restrict__ src, unsigned short* __restrict__ dst) {
    float4 a = *(const float4*)src;
    float4 b = *(const float4*)(src + 4);
    uint4 p;
    p.x = pack_bf16x2(a.x, a.y); p.y = pack_bf16x2(a.z, a.w);
    p.z = pack_bf16x2(b.x, b.y); p.w = pack_bf16x2(b.z, b.w);
    *(uint4*)dst = p;
}

// ---------- fused prep ----------
// blocks: [0,1024) WqT | [1024,2048) WvT | [2048,3072) WoutT |
//         [3072,3584) WkB strided cast | [3584,4608) x cast
__global__ __launch_bounds__(256) void prep_kernel(
    const float* __restrict__ Wq, const float* __restrict__ Wkv,
    const float* __restrict__ Wout, const float* __restrict__ x,
    unsigned short* __restrict__ WqT, unsigned short* __restrict__ WkB,
    unsigned short* __restrict__ WvT, unsigned short* __restrict__ WoutT,
    unsigned short* __restrict__ xb) {
    int id = blockIdx.x, tid = threadIdx.x;
    if (id < 1024) { transpose_tile(Wq,   1024, 0,    WqT,   1024, id & 31, id >> 5, tid); return; }
    id -= 1024;
    if (id < 1024) { transpose_tile(Wkv,  2048, 1024, WvT,   1024, id & 31, id >> 5, tid); return; }
    id -= 1024;
    if (id < 1024) { transpose_tile(Wout, 1024, 0,    WoutT, 1024, id & 31, id >> 5, tid); return; }
    id -= 1024;
    if (id < 512) {   // WkB[c][d] = bf16(Wkv[c][d]), d<1024
        long e = ((long)id * 256 + tid) * 8;
        long row = e >> 10, col = e & 1023;
        cast8(Wkv + row * 2048 + col, WkB + e);
        return;
    }
    id -= 512;
    { long e = ((long)id * 256 + tid) * 8; cast8(x + e, xb + e); }
}

// ---------- universal GEMM: 128x64 tile, BK=32, batched+strided ----------
// C[.,N] = A[.,K](bf16) @ Bt[N,K](bf16)^T. 4 waves: wave w owns M-rows
// [w*32, w*32+32) x all 64 N-cols via 2x4 grid of 16x16x32 MFMA.
__global__ __launch_bounds__(256, 4) void gemm64_kernel(
    const unsigned short* __restrict__ A, long sA, int lda,
    const unsigned short* __restrict__ Bt, long sB, int ldb,
    void* __restrict__ C, long sC, int ldc,
    const float* __restrict__ bias, int K, int out_bf16) {
    __shared__ unsigned short As[128 * 32];   // 8 KB
    __shared__ unsigned short Bs[64 * 32];    // 4 KB

    const int tid = threadIdx.x, wave = tid >> 6, lane = tid & 63;
    const int z = blockIdx.z;
    A  += (long)z * sA;
    Bt += (long)z * sB;
    const int m0 = blockIdx.y * 128, n0 = blockIdx.x * 64;

    floatx4 acc[2][4];
#pragma unroll
    for (int i = 0; i < 2; ++i)
#pragma unroll
        for (int j = 0; j < 4; ++j) acc[i][j] = (floatx4)0.0f;

    // staging: wave w covers A-rows w*32..+31 (2 issues), B-rows w*16..+15 (1 issue)
    const int kofs = (lane & 3) * 8;
    const unsigned short* aAddr = A  + (long)(m0 + wave * 32 + (lane >> 2)) * lda + kofs;
    const unsigned short* bAddr = Bt + (long)(n0 + wave * 16 + (lane >> 2)) * ldb + kofs;
    unsigned short* asBase = &As[wave * 1024];
    unsigned short* bsBase = &Bs[wave * 512];

    const int frm = lane & 15, fk = (lane >> 4) * 8;

    for (int kk = 0; kk < K; kk += 32) {
        __syncthreads();
        async_load16(aAddr + kk,                  asBase);
        async_load16(aAddr + (long)16 * lda + kk, asBase + 512);
        async_load16(bAddr + kk,                  bsBase);
        __syncthreads();

        short8 afrag[2], bfrag[4];
#pragma unroll
        for (int rt = 0; rt < 2; ++rt)
            afrag[rt] = *(const short8*)&As[(wave * 32 + rt * 16 + frm) * 32 + fk];
#pragma unroll
        for (int ct = 0; ct < 4; ++ct)
            bfrag[ct] = *(const short8*)&Bs[(ct * 16 + frm) * 32 + fk];
#pragma unroll
        for (int rt = 0; rt < 2; ++rt)
#pragma unroll
            for (int ct = 0; ct < 4; ++ct)
                acc[rt][ct] = __builtin_amdgcn_mfma_f32_16x16x32_bf16(
                    afrag[rt], bfrag[ct], acc[rt][ct], 0, 0, 0);
    }

    // epilogue: C/D layout col=lane&15, row=(lane>>4)*4+r
    const int orow0 = m0 + wave * 32 + (lane >> 4) * 4;
    const int ocol0 = n0 + (lane & 15);
    if (out_bf16) {
        unsigned short* Cb = (unsigned short*)C + (long)z * sC;
#pragma unroll
        for (int rt = 0; rt < 2; ++rt)
#pragma unroll
            for (int r = 0; r < 4; ++r) {
                long row = orow0 + rt * 16 + r;
#pragma unroll
                for (int ct = 0; ct < 4; ++ct)
                    Cb[row * ldc + ocol0 + ct * 16] = f32_to_bf16(acc[rt][ct][r]);
            }
    } else {
        float* Cf = (float*)C + (long)z * sC;
#pragma unroll
        for (int rt = 0; rt < 2; ++rt)
#pragma unroll
            for (int r = 0; r < 4; ++r) {
                long row = orow0 + rt * 16 + r;
#pragma unroll
                for (int ct = 0; ct < 4; ++ct) {
                    int col = ocol0 + ct * 16;
                    float v = acc[rt][ct][r];
                    if (bias) v += bias[col];
                    Cf[row * ldc + col] = v;
                }
            }
    }
}

// ---------- fused attention: s = qt.ctx^T -> softmax -> wctx = p.ctx ----------
// one block per (b,i); 32 ctx rows j=i+128t loaded once (fp32->bf16 LDS).
// qt layout [bi][h][1024]: A-frags preloaded into 32 VGPRs (no LDS tile).
#define CLD 1032   // LDS row stride (elems) for ctx: breaks b128 bank aliasing
__global__ __launch_bounds__(256, 2) void attn_fused_kernel(
    const float* __restrict__ ctx,          // fp32 [16*4096][1024]
    const unsigned short* __restrict__ qt,  // bf16 [2048][16][1024]
    unsigned short* __restrict__ wctx) {    // bf16 [2048][16][1024]
    __shared__ unsigned short ctx_t[32 * CLD];   // 66 KB
    __shared__ float sred[4 * 512];              // 8 KB
    __shared__ float s_f[512];                   // 2 KB
    __shared__ float mxs[16], inv_[16];
    __shared__ unsigned short p_l[16 * 40];      // p in A-layout [h][t], padded

    const int tid = threadIdx.x, wave = tid >> 6, lane = tid & 63;
    const int bi = blockIdx.x;
    const int b = bi >> 7, i = bi & 127;
    const int frm = lane & 15, fk = (lane >> 4) * 8;

    // preload qt A-frags into registers: lane needs head row frm,
    // k-range wave*256 + it*32 + fk .. +8
    short8 af[8];
    const unsigned short* qbase =
        qt + (long)bi * 16384 + (long)frm * 1024 + wave * 256 + fk;
#pragma unroll
    for (int it = 0; it < 8; ++it) af[it] = *(const short8*)(qbase + it * 32);

    // load ctx rows j=i+128t (fp32 -> bf16)
#pragma unroll
    for (int rr = 0; rr < 16; ++rr) {
        int idx = rr * 2048 + tid * 8;
        int t = idx >> 10, c = idx & 1023;
        cast8(ctx + ((long)b * 4096 + i + t * 128) * 1024 + c, &ctx_t[t * CLD + c]);
    }
    __syncthreads();

    // s partials: wave w covers k in [w*256, w*256+256)
    floatx4 acc0 = (floatx4)0.0f, acc1 = (floatx4)0.0f;
#pragma unroll
    for (int it = 0; it < 8; ++it) {
        int kk = wave * 256 + it * 32;
        short8 b0 = *(const short8*)&ctx_t[frm * CLD + kk + fk];
        short8 b1 = *(const short8*)&ctx_t[(16 + frm) * CLD + kk + fk];
        acc0 = __builtin_amdgcn_mfma_f32_16x16x32_bf16(af[it], b0, acc0, 0, 0, 0);
        acc1 = __builtin_amdgcn_mfma_f32_16x16x32_bf16(af[it], b1, acc1, 0, 0, 0);
    }
    // C-layout: t = lane&15 (+16 for acc1), h = (lane>>4)*4 + r; store sred[t*16+h]
#pragma unroll
    for (int r = 0; r < 4; ++r) {
        sred[wave * 512 + frm * 16 + (lane >> 4) * 4 + r]        = acc0[r];
        sred[wave * 512 + (16 + frm) * 16 + (lane >> 4) * 4 + r] = acc1[r];
    }
    __syncthreads();
    // cross-wave reduce + scale
#pragma unroll
    for (int half = 0; half < 2; ++half) {
        int idx = half * 256 + tid;
        s_f[idx] = (sred[idx] + sred[512 + idx] + sred[1024 + idx] + sred[1536 + idx]) * 0.125f;
    }
    __syncthreads();
    // softmax over t (32) per h
    if (tid < 16) {
        int h = tid;
        float m = -1e30f;
        for (int t = 0; t < 32; ++t) m = fmaxf(m, s_f[t * 16 + h]);
        float den = 0.0f;
        for (int t = 0; t < 32; ++t) den += __expf(s_f[t * 16 + h] - m);
        mxs[h] = m; inv_[h] = 1.0f / den;
    }
    __syncthreads();
#pragma unroll
    for (int half = 0; half < 2; ++half) {
        int idx = half * 256 + tid;
        int t = idx >> 4, h = idx & 15;
        p_l[h * 40 + t] = f32_to_bf16(__expf(s_f[idx] - mxs[h]) * inv_[h]);
    }
    __syncthreads();

    // wctx[h][c] = sum_t p[h][t] * ctx[t][c]; wave covers c-range wave*256
    short8 ap;
#pragma unroll
    for (int j = 0; j < 8; ++j) ap[j] = (short)p_l[frm * 40 + fk + j];
#pragma unroll 4
    for (int nt = 0; nt < 16; ++nt) {
        int c0 = wave * 256 + nt * 16;
        short8 bt;
#pragma unroll
        for (int j = 0; j < 8; ++j) bt[j] = (short)ctx_t[(fk + j) * CLD + c0 + frm];
        floatx4 wacc = __builtin_amdgcn_mfma_f32_16x16x32_bf16(ap, bt, (floatx4)0.0f, 0, 0, 0);
#pragma unroll
        for (int r = 0; r < 4; ++r) {
            int h = (lane >> 4) * 4 + r;
            wctx[(long)bi * 16384 + (long)h * 1024 + c0 + frm] = f32_to_bf16(wacc[r]);
        }
    }
}

// ---------- launch ----------
extern "C" void kernel_launch(void* const* d_in, const int* in_sizes, int n_in,
                              void* d_out, int out_size, void* d_ws, size_t ws_size,
                              hipStream_t stream) {
    const float* x       = (const float*)d_in[0];   // [16,128,1024]
    const float* context = (const float*)d_in[1];   // [16,4096,1024]
    const float* Wq      = (const float*)d_in[2];   // [1024,1024]
    const float* Wkv     = (const float*)d_in[3];   // [1024,2048]
    const float* Wout    = (const float*)d_in[4];   // [1024,1024]
    const float* bout    = (const float*)d_in[5];   // [1024]
    float* out = (float*)d_out;                     // [16,128,1024] fp32

    char* ws = (char*)d_ws;
    unsigned short* WqT   = (unsigned short*)(ws);                       // 2MB
    unsigned short* WkB   = (unsigned short*)(ws + (2ll  << 20));        // 2MB (k-half of Wkv, bf16)
    unsigned short* WvT   = (unsigned short*)(ws + (4ll  << 20));        // 2MB (v-half, transposed)
    unsigned short* WoutT = (unsigned short*)(ws + (6ll  << 20));        // 2MB
    unsigned short* xb    = (unsigned short*)(ws + (8ll  << 20));        // 4MB
    unsigned short* qb    = (unsigned short*)(ws + (12ll << 20));        // 4MB
    unsigned short* aob   = (unsigned short*)(ws + (16ll << 20));        // 4MB
    unsigned short* qtb   = (unsigned short*)(ws + (32ll << 20));        // 64MB [bi][16][1024]
    unsigned short* wctxb = (unsigned short*)(ws + (96ll << 20));        // 64MB [bi][16][1024]

    // prep: weight transposes/casts + x cast
    prep_kernel<<<4608, 256, 0, stream>>>(Wq, Wkv, Wout, x, WqT, WkB, WvT, WoutT, xb);

    // q = x @ Wq                       [2048,1024] bf16
    gemm64_kernel<<<dim3(16, 16, 1), 256, 0, stream>>>(
        xb, 0, 1024, WqT, 0, 1024, qb, 0, 1024, nullptr, 1024, 1);
    // qt[bi][h][c] = q_h[bi] @ Wk_h^T  (K=64 per head, z=h)
    gemm64_kernel<<<dim3(16, 16, 16), 256, 0, stream>>>(
        qb, 64, 1024, WkB, 64, 1024, qtb, 1024, 16384, nullptr, 64, 1);
    // fused: s -> softmax -> wctx      [2048][16][1024] bf16
    attn_fused_kernel<<<2048, 256, 0, stream>>>(context, qtb, wctxb);
    // aob[bi][h*64+d] = wctx_h[bi] @ Wv_h   (K=1024, z=h)
    gemm64_kernel<<<dim3(1, 16, 16), 256, 0, stream>>>(
        wctxb, 1024, 16384, WvT, (long)64 * 1024, 1024, aob, 64, 1024, nullptr, 1024, 1);
    // out = aob @ Wout + bout          [2048,1024] fp32
    gemm64_kernel<<<dim3(16, 16, 1), 256, 0, stream>>>(
        aob, 0, 1024, WoutT, 0, 1024, out, 0, 1024, bout, 1024, 0);
}

// Round 6
// 472.783 us; speedup vs baseline: 2.3810x; 1.0129x over previous
//
#include <hip/hip_runtime.h>
#include <hip/hip_bf16.h>

typedef __attribute__((ext_vector_type(8))) short short8;
typedef __attribute__((ext_vector_type(4))) float floatx4;

// ---------- helpers ----------
__device__ __forceinline__ unsigned short f32_to_bf16(float f) {
    unsigned int u = __builtin_bit_cast(unsigned int, f);
    u = (u + 0x7FFFu + ((u >> 16) & 1u)) >> 16;   // RNE
    return (unsigned short)u;
}
__device__ __forceinline__ unsigned int pack_bf16x2(float lo, float hi) {
    return (unsigned int)f32_to_bf16(lo) | ((unsigned int)f32_to_bf16(hi) << 16);
}
// async global->LDS, 16B per lane; LDS dest = wave-uniform base + lane*16
__device__ __forceinline__ void async_load16(const unsigned short* g, unsigned short* l) {
    __builtin_amdgcn_global_load_lds(
        (const __attribute__((address_space(1))) void*)g,
        (__attribute__((address_space(3))) void*)l, 16, 0, 0);
}

// ---------- transpose tile: Wt[n][k] = W[k][n_off+n], 32x32 ----------
__device__ __forceinline__ void transpose_tile(
    const float* __restrict__ W, int src_ld, int n_off,
    unsigned short* __restrict__ Wt, int dst_ld, int nb, int kb, int tid) {
    __shared__ float tile[32][33];
    int n0 = nb * 32, k0 = kb * 32;
    int tx = tid & 31, ty = tid >> 5;    // ty 0..7
#pragma unroll
    for (int p = 0; p < 4; ++p) {
        int r = ty + 8 * p;
        tile[r][tx] = W[(long)(k0 + r) * src_ld + n_off + n0 + tx];
    }
    __syncthreads();
#pragma unroll
    for (int p = 0; p < 4; ++p) {
        int r = ty + 8 * p;
        Wt[(long)(n0 + r) * dst_ld + k0 + tx] = f32_to_bf16(tile[tx][r]);
    }
}

__device__ __forceinline__ void cast8(
    const float* __restrict__ src, unsigned short* __restrict__ dst) {
    float4 a = *(const float4*)src;
    float4 b = *(const float4*)(src + 4);
    uint4 p;
    p.x = pack_bf16x2(a.x, a.y); p.y = pack_bf16x2(a.z, a.w);
    p.z = pack_bf16x2(b.x, b.y); p.w = pack_bf16x2(b.z, b.w);
    *(uint4*)dst = p;
}

// ---------- fused prep ----------
// blocks: [0,1024) WqT | [1024,2048) WvT | [2048,3072) WoutT |
//         [3072,3584) WkB strided cast | [3584,4608) x cast
__global__ __launch_bounds__(256) void prep_kernel(
    const float* __restrict__ Wq, const float* __restrict__ Wkv,
    const float* __restrict__ Wout, const float* __restrict__ x,
    unsigned short* __restrict__ WqT, unsigned short* __restrict__ WkB,
    unsigned short* __restrict__ WvT, unsigned short* __restrict__ WoutT,
    unsigned short* __restrict__ xb) {
    int id = blockIdx.x, tid = threadIdx.x;
    if (id < 1024) { transpose_tile(Wq,   1024, 0,    WqT,   1024, id & 31, id >> 5, tid); return; }
    id -= 1024;
    if (id < 1024) { transpose_tile(Wkv,  2048, 1024, WvT,   1024, id & 31, id >> 5, tid); return; }
    id -= 1024;
    if (id < 1024) { transpose_tile(Wout, 1024, 0,    WoutT, 1024, id & 31, id >> 5, tid); return; }
    id -= 1024;
    if (id < 512) {   // WkB[c][d] = bf16(Wkv[c][d]), d<1024
        long e = ((long)id * 256 + tid) * 8;
        long row = e >> 10, col = e & 1023;
        cast8(Wkv + row * 2048 + col, WkB + e);
        return;
    }
    id -= 512;
    { long e = ((long)id * 256 + tid) * 8; cast8(x + e, xb + e); }
}

// ---------- GEMM 128x64 tile (used for qt: many small-K blocks) ----------
__global__ __launch_bounds__(256, 4) void gemm64_kernel(
    const unsigned short* __restrict__ A, long sA, int lda,
    const unsigned short* __restrict__ Bt, long sB, int ldb,
    void* __restrict__ C, long sC, int ldc,
    const float* __restrict__ bias, int K, int out_bf16) {
    __shared__ unsigned short As[128 * 32];   // 8 KB
    __shared__ unsigned short Bs[64 * 32];    // 4 KB

    const int tid = threadIdx.x, wave = tid >> 6, lane = tid & 63;
    const int z = blockIdx.z;
    A  += (long)z * sA;
    Bt += (long)z * sB;
    const int m0 = blockIdx.y * 128, n0 = blockIdx.x * 64;

    floatx4 acc[2][4];
#pragma unroll
    for (int i = 0; i < 2; ++i)
#pragma unroll
        for (int j = 0; j < 4; ++j) acc[i][j] = (floatx4)0.0f;

    const int kofs = (lane & 3) * 8;
    const unsigned short* aAddr = A  + (long)(m0 + wave * 32 + (lane >> 2)) * lda + kofs;
    const unsigned short* bAddr = Bt + (long)(n0 + wave * 16 + (lane >> 2)) * ldb + kofs;
    unsigned short* asBase = &As[wave * 1024];
    unsigned short* bsBase = &Bs[wave * 512];

    const int frm = lane & 15, fk = (lane >> 4) * 8;

    for (int kk = 0; kk < K; kk += 32) {
        __syncthreads();
        async_load16(aAddr + kk,                  asBase);
        async_load16(aAddr + (long)16 * lda + kk, asBase + 512);
        async_load16(bAddr + kk,                  bsBase);
        __syncthreads();

        short8 afrag[2], bfrag[4];
#pragma unroll
        for (int rt = 0; rt < 2; ++rt)
            afrag[rt] = *(const short8*)&As[(wave * 32 + rt * 16 + frm) * 32 + fk];
#pragma unroll
        for (int ct = 0; ct < 4; ++ct)
            bfrag[ct] = *(const short8*)&Bs[(ct * 16 + frm) * 32 + fk];
#pragma unroll
        for (int rt = 0; rt < 2; ++rt)
#pragma unroll
            for (int ct = 0; ct < 4; ++ct)
                acc[rt][ct] = __builtin_amdgcn_mfma_f32_16x16x32_bf16(
                    afrag[rt], bfrag[ct], acc[rt][ct], 0, 0, 0);
    }

    const int orow0 = m0 + wave * 32 + (lane >> 4) * 4;
    const int ocol0 = n0 + (lane & 15);
    if (out_bf16) {
        unsigned short* Cb = (unsigned short*)C + (long)z * sC;
#pragma unroll
        for (int rt = 0; rt < 2; ++rt)
#pragma unroll
            for (int r = 0; r < 4; ++r) {
                long row = orow0 + rt * 16 + r;
#pragma unroll
                for (int ct = 0; ct < 4; ++ct)
                    Cb[row * ldc + ocol0 + ct * 16] = f32_to_bf16(acc[rt][ct][r]);
            }
    } else {
        float* Cf = (float*)C + (long)z * sC;
#pragma unroll
        for (int rt = 0; rt < 2; ++rt)
#pragma unroll
            for (int r = 0; r < 4; ++r) {
                long row = orow0 + rt * 16 + r;
#pragma unroll
                for (int ct = 0; ct < 4; ++ct) {
                    int col = ocol0 + ct * 16;
                    float v = acc[rt][ct][r];
                    if (bias) v += bias[col];
                    Cf[row * ldc + col] = v;
                }
            }
    }
}

// ---------- GEMM 64x64 tile: doubles grid for 256-block-class launches ----------
// 2 blocks/CU co-resident -> one block's MFMA hides the other's vmcnt drain.
__global__ __launch_bounds__(256, 4) void gemm64s_kernel(
    const unsigned short* __restrict__ A, long sA, int lda,
    const unsigned short* __restrict__ Bt, long sB, int ldb,
    void* __restrict__ C, long sC, int ldc,
    const float* __restrict__ bias, int K, int out_bf16) {
    __shared__ unsigned short As[64 * 32];   // 4 KB
    __shared__ unsigned short Bs[64 * 32];   // 4 KB

    const int tid = threadIdx.x, wave = tid >> 6, lane = tid & 63;
    const int z = blockIdx.z;
    A  += (long)z * sA;
    Bt += (long)z * sB;
    const int m0 = blockIdx.y * 64, n0 = blockIdx.x * 64;

    floatx4 acc[4];
#pragma unroll
    for (int j = 0; j < 4; ++j) acc[j] = (floatx4)0.0f;

    // staging: wave w covers A-rows w*16..+15 and B-rows w*16..+15, 1 issue each
    const int kofs = (lane & 3) * 8;
    const unsigned short* aAddr = A  + (long)(m0 + wave * 16 + (lane >> 2)) * lda + kofs;
    const unsigned short* bAddr = Bt + (long)(n0 + wave * 16 + (lane >> 2)) * ldb + kofs;
    unsigned short* asBase = &As[wave * 512];
    unsigned short* bsBase = &Bs[wave * 512];

    const int frm = lane & 15, fk = (lane >> 4) * 8;

    for (int kk = 0; kk < K; kk += 32) {
        __syncthreads();
        async_load16(aAddr + kk, asBase);
        async_load16(bAddr + kk, bsBase);
        __syncthreads();

        short8 afrag = *(const short8*)&As[(wave * 16 + frm) * 32 + fk];
        short8 bfrag[4];
#pragma unroll
        for (int ct = 0; ct < 4; ++ct)
            bfrag[ct] = *(const short8*)&Bs[(ct * 16 + frm) * 32 + fk];
#pragma unroll
        for (int ct = 0; ct < 4; ++ct)
            acc[ct] = __builtin_amdgcn_mfma_f32_16x16x32_bf16(
                afrag, bfrag[ct], acc[ct], 0, 0, 0);
    }

    const int orow0 = m0 + wave * 16 + (lane >> 4) * 4;
    const int ocol0 = n0 + (lane & 15);
    if (out_bf16) {
        unsigned short* Cb = (unsigned short*)C + (long)z * sC;
#pragma unroll
        for (int r = 0; r < 4; ++r) {
            long row = orow0 + r;
#pragma unroll
            for (int ct = 0; ct < 4; ++ct)
                Cb[row * ldc + ocol0 + ct * 16] = f32_to_bf16(acc[ct][r]);
        }
    } else {
        float* Cf = (float*)C + (long)z * sC;
#pragma unroll
        for (int r = 0; r < 4; ++r) {
            long row = orow0 + r;
#pragma unroll
            for (int ct = 0; ct < 4; ++ct) {
                int col = ocol0 + ct * 16;
                float v = acc[ct][r];
                if (bias) v += bias[col];
                Cf[row * ldc + col] = v;
            }
        }
    }
}

// ---------- fused attention: s = qt.ctx^T -> softmax -> wctx = p.ctx ----------
// one block per (b,i); 32 ctx rows j=i+128t loaded once (fp32->bf16 LDS).
// qt layout [bi][h][1024]: A-frags preloaded into 32 VGPRs (no LDS tile).
#define CLD 1032   // LDS row stride (elems): 16B-aligned rows, 2-way (free) on b128 row reads
__global__ __launch_bounds__(256, 2) void attn_fused_kernel(
    const float* __restrict__ ctx,          // fp32 [16*4096][1024]
    const unsigned short* __restrict__ qt,  // bf16 [2048][16][1024]
    unsigned short* __restrict__ wctx) {    // bf16 [2048][16][1024]
    __shared__ unsigned short ctx_t[32 * CLD];   // 66 KB
    __shared__ float sred[4 * 512];              // 8 KB
    __shared__ float s_f[512];                   // 2 KB
    __shared__ float mxs[16], inv_[16];
    __shared__ unsigned short p_l[16 * 40];      // p in A-layout [h][t], padded

    const int tid = threadIdx.x, wave = tid >> 6, lane = tid & 63;
    const int bi = blockIdx.x;
    const int b = bi >> 7, i = bi & 127;
    const int frm = lane & 15, fk = (lane >> 4) * 8;

    // preload qt A-frags into registers: lane needs head row frm,
    // k-range wave*256 + it*32 + fk .. +8
    short8 af[8];
    const unsigned short* qbase =
        qt + (long)bi * 16384 + (long)frm * 1024 + wave * 256 + fk;
#pragma unroll
    for (int it = 0; it < 8; ++it) af[it] = *(const short8*)(qbase + it * 32);

    // load ctx rows j=i+128t (fp32 -> bf16)
#pragma unroll
    for (int rr = 0; rr < 16; ++rr) {
        int idx = rr * 2048 + tid * 8;
        int t = idx >> 10, c = idx & 1023;
        cast8(ctx + ((long)b * 4096 + i + t * 128) * 1024 + c, &ctx_t[t * CLD + c]);
    }
    __syncthreads();

    // s partials: wave w covers k in [w*256, w*256+256)
    floatx4 acc0 = (floatx4)0.0f, acc1 = (floatx4)0.0f;
#pragma unroll
    for (int it = 0; it < 8; ++it) {
        int kk = wave * 256 + it * 32;
        short8 b0 = *(const short8*)&ctx_t[frm * CLD + kk + fk];
        short8 b1 = *(const short8*)&ctx_t[(16 + frm) * CLD + kk + fk];
        acc0 = __builtin_amdgcn_mfma_f32_16x16x32_bf16(af[it], b0, acc0, 0, 0, 0);
        acc1 = __builtin_amdgcn_mfma_f32_16x16x32_bf16(af[it], b1, acc1, 0, 0, 0);
    }
    // C-layout: t = lane&15 (+16 for acc1), h = (lane>>4)*4 + r; store sred[t*16+h]
#pragma unroll
    for (int r = 0; r < 4; ++r) {
        sred[wave * 512 + frm * 16 + (lane >> 4) * 4 + r]        = acc0[r];
        sred[wave * 512 + (16 + frm) * 16 + (lane >> 4) * 4 + r] = acc1[r];
    }
    __syncthreads();
    // cross-wave reduce + scale
#pragma unroll
    for (int half = 0; half < 2; ++half) {
        int idx = half * 256 + tid;
        s_f[idx] = (sred[idx] + sred[512 + idx] + sred[1024 + idx] + sred[1536 + idx]) * 0.125f;
    }
    __syncthreads();
    // softmax over t (32) per h
    if (tid < 16) {
        int h = tid;
        float m = -1e30f;
        for (int t = 0; t < 32; ++t) m = fmaxf(m, s_f[t * 16 + h]);
        float den = 0.0f;
        for (int t = 0; t < 32; ++t) den += __expf(s_f[t * 16 + h] - m);
        mxs[h] = m; inv_[h] = 1.0f / den;
    }
    __syncthreads();
#pragma unroll
    for (int half = 0; half < 2; ++half) {
        int idx = half * 256 + tid;
        int t = idx >> 4, h = idx & 15;
        p_l[h * 40 + t] = f32_to_bf16(__expf(s_f[idx] - mxs[h]) * inv_[h]);
    }
    __syncthreads();

    // wctx[h][c] = sum_t p[h][t] * ctx[t][c]; wave covers c-range wave*256
    short8 ap;
#pragma unroll
    for (int j = 0; j < 8; ++j) ap[j] = (short)p_l[frm * 40 + fk + j];
#pragma unroll 4
    for (int nt = 0; nt < 16; ++nt) {
        int c0 = wave * 256 + nt * 16;
        short8 bt;
#pragma unroll
        for (int j = 0; j < 8; ++j) bt[j] = (short)ctx_t[(fk + j) * CLD + c0 + frm];
        floatx4 wacc = __builtin_amdgcn_mfma_f32_16x16x32_bf16(ap, bt, (floatx4)0.0f, 0, 0, 0);
#pragma unroll
        for (int r = 0; r < 4; ++r) {
            int h = (lane >> 4) * 4 + r;
            wctx[(long)bi * 16384 + (long)h * 1024 + c0 + frm] = f32_to_bf16(wacc[r]);
        }
    }
}

// ---------- launch ----------
extern "C" void kernel_launch(void* const* d_in, const int* in_sizes, int n_in,
                              void* d_out, int out_size, void* d_ws, size_t ws_size,
                              hipStream_t stream) {
    const float* x       = (const float*)d_in[0];   // [16,128,1024]
    const float* context = (const float*)d_in[1];   // [16,4096,1024]
    const float* Wq      = (const float*)d_in[2];   // [1024,1024]
    const float* Wkv     = (const float*)d_in[3];   // [1024,2048]
    const float* Wout    = (const float*)d_in[4];   // [1024,1024]
    const float* bout    = (const float*)d_in[5];   // [1024]
    float* out = (float*)d_out;                     // [16,128,1024] fp32

    char* ws = (char*)d_ws;
    unsigned short* WqT   = (unsigned short*)(ws);                       // 2MB
    unsigned short* WkB   = (unsigned short*)(ws + (2ll  << 20));        // 2MB (k-half of Wkv, bf16)
    unsigned short* WvT   = (unsigned short*)(ws + (4ll  << 20));        // 2MB (v-half, transposed)
    unsigned short* WoutT = (unsigned short*)(ws + (6ll  << 20));        // 2MB
    unsigned short* xb    = (unsigned short*)(ws + (8ll  << 20));        // 4MB
    unsigned short* qb    = (unsigned short*)(ws + (12ll << 20));        // 4MB
    unsigned short* aob   = (unsigned short*)(ws + (16ll << 20));        // 4MB
    unsigned short* qtb   = (unsigned short*)(ws + (32ll << 20));        // 64MB [bi][16][1024]
    unsigned short* wctxb = (unsigned short*)(ws + (96ll << 20));        // 64MB [bi][16][1024]

    // prep: weight transposes/casts + x cast
    prep_kernel<<<4608, 256, 0, stream>>>(Wq, Wkv, Wout, x, WqT, WkB, WvT, WoutT, xb);

    // q = x @ Wq                       [2048,1024] bf16   (512 blocks, 2/CU)
    gemm64s_kernel<<<dim3(16, 32, 1), 256, 0, stream>>>(
        xb, 0, 1024, WqT, 0, 1024, qb, 0, 1024, nullptr, 1024, 1);
    // qt[bi][h][c] = q_h[bi] @ Wk_h^T  (K=64 per head, z=h; 4096 blocks)
    gemm64_kernel<<<dim3(16, 16, 16), 256, 0, stream>>>(
        qb, 64, 1024, WkB, 64, 1024, qtb, 1024, 16384, nullptr, 64, 1);
    // fused: s -> softmax -> wctx      [2048][16][1024] bf16
    attn_fused_kernel<<<2048, 256, 0, stream>>>(context, qtb, wctxb);
    // aob[bi][h*64+d] = wctx_h[bi] @ Wv_h   (K=1024, z=h; 512 blocks)
    gemm64s_kernel<<<dim3(1, 32, 16), 256, 0, stream>>>(
        wctxb, 1024, 16384, WvT, (long)64 * 1024, 1024, aob, 64, 1024, nullptr, 1024, 1);
    // out = aob @ Wout + bout          [2048,1024] fp32   (512 blocks, 2/CU)
    gemm64s_kernel<<<dim3(16, 32, 1), 256, 0, stream>>>(
        aob, 0, 1024, WoutT, 0, 1024, out, 0, 1024, bout, 1024, 0);
}